// Round 1
// baseline (408.415 us; speedup 1.0000x reference)
//
#include <hip/hip_runtime.h>
#include <cstdint>
#include <cstddef>
#include <math.h>

#define B_ 8
#define H_ 4
#define NN 2048
#define DIN 128
#define DOUT 128
#define HO (H_ * DOUT)   // 512

typedef __attribute__((ext_vector_type(4))) float f32x4;
typedef __attribute__((ext_vector_type(8))) short s16x8;
typedef __attribute__((ext_vector_type(4))) short s16x4;

__device__ __forceinline__ unsigned short f2bf(float f) {
    union { float f; unsigned u; } v; v.f = f;
    unsigned r = v.u + 0x7fffu + ((v.u >> 16) & 1u);   // RNE
    return (unsigned short)(r >> 16);
}

__device__ __forceinline__ void gload_lds16(const void* g, void* l) {
    __builtin_amdgcn_global_load_lds(
        (const __attribute__((address_space(1))) unsigned int*)g,
        (__attribute__((address_space(3))) unsigned int*)l, 16, 0, 0);
}

// ---------------------------------------------------------------------------
// K1: column sums of adj (partials, deterministic) + adj pass-through copy.
// grid (64 chunks, B_), 256 threads. Each chunk = 32 rows.
// Thread t owns cols [4t,4t+3] and [1024+4t, 1024+4t+3].
__global__ __launch_bounds__(256) void k_colsum_copy(
        const float* __restrict__ adj, float* __restrict__ out_adj,
        float* __restrict__ partial) {
    const int b = blockIdx.y, chunk = blockIdx.x, t = threadIdx.x;
    const float* src = adj + (size_t)b * NN * NN;
    float* dst = out_adj + (size_t)b * NN * NN;
    f32x4 s0 = {0.f, 0.f, 0.f, 0.f}, s1 = {0.f, 0.f, 0.f, 0.f};
    const int r0 = chunk * 32;
    for (int r = r0; r < r0 + 32; ++r) {
        const f32x4* row = (const f32x4*)(src + (size_t)r * NN);
        f32x4* orow = (f32x4*)(dst + (size_t)r * NN);
        f32x4 a = row[t], c = row[t + 256];
        orow[t] = a; orow[t + 256] = c;
        s0 += a; s1 += c;
    }
    float* p = partial + ((size_t)chunk * B_ + b) * NN;
    *(f32x4*)(p + 4 * t) = s0;
    *(f32x4*)(p + 1024 + 4 * t) = s1;
}

// ---------------------------------------------------------------------------
// K2: d = rsqrt(colsum); also copy pooled through. 64 blocks x 256.
__global__ __launch_bounds__(256) void k_finalize(
        const float* __restrict__ partial, float* __restrict__ dvec,
        const float* __restrict__ pooled, float* __restrict__ out_pooled) {
    const int i = blockIdx.x * 256 + threadIdx.x;   // 0..16383 (= b*2048+n)
    float s = 0.f;
    for (int c = 0; c < 64; ++c) s += partial[(size_t)c * (B_ * NN) + i];
    dvec[i] = 1.0f / sqrtf(s);
    if (i < B_ * DOUT) out_pooled[i] = pooled[i];
}

// ---------------------------------------------------------------------------
// K3: adjn[b][m][n] = bf16(d[b][m] * adj[b][m][n] * d[b][n]). Grid-stride f32x4.
__global__ __launch_bounds__(256) void k_adjn(
        const float* __restrict__ adj, const float* __restrict__ dvec,
        unsigned short* __restrict__ adjn) {
    const size_t total = (size_t)B_ * NN * NN / 4;
    const size_t stride = (size_t)gridDim.x * blockDim.x;
    for (size_t idx = (size_t)blockIdx.x * blockDim.x + threadIdx.x; idx < total; idx += stride) {
        size_t e = idx * 4;
        int b = (int)(e >> 22);                 // / (2048*2048)
        int rem = (int)(e & ((1u << 22) - 1));
        int m = rem >> 11, n = rem & (NN - 1);
        f32x4 a = *(const f32x4*)(adj + e);
        float dm = dvec[b * NN + m];
        f32x4 dn = *(const f32x4*)(dvec + b * NN + n);
        f32x4 v = a * dm;
        v *= dn;
        s16x4 o = { (short)f2bf(v.x), (short)f2bf(v.y), (short)f2bf(v.z), (short)f2bf(v.w) };
        *(s16x4*)(adjn + e) = o;
    }
}

// ---------------------------------------------------------------------------
// K4: support^T[b][h*128+o][n] = bf16( sum_i x[b][h][n][i] * W[h][i][o] ).
// One block per (n-tile of 128, h, b); 4 waves each 64x64; K = 128 in one shot.
// LDS padded (+8) to kill the stride-256B bank conflict on ds_read_b128.
__global__ __launch_bounds__(256) void k_support(
        const float* __restrict__ x, const float* __restrict__ w,
        unsigned short* __restrict__ sT) {
    constexpr int LDA = DIN + 8;   // 136: row stride 272B -> 2-way conflict only
    __shared__ unsigned short As[128 * LDA];   // x tile   [n][i]
    __shared__ unsigned short Bs[DOUT * LDA];  // W^T tile [o][i]
    const int nt = blockIdx.x, h = blockIdx.y, b = blockIdx.z, t = threadIdx.x;

    const float* xp = x + (((size_t)b * H_ + h) * NN + (size_t)nt * 128) * DIN;
    #pragma unroll
    for (int it = 0; it < 16; ++it) {
        int v = t + it * 256;                 // float4 index; row = v/32, col4 = v%32
        int row = v >> 5, c4 = (v & 31) * 4;
        f32x4 a = ((const f32x4*)xp)[v];
        s16x4 s = { (short)f2bf(a.x), (short)f2bf(a.y), (short)f2bf(a.z), (short)f2bf(a.w) };
        *(s16x4*)(As + row * LDA + c4) = s;
    }
    const float* wp = w + (size_t)h * DIN * DOUT;
    #pragma unroll
    for (int it = 0; it < 16; ++it) {
        int v = t + it * 256;                 // W[i][o]: i = v/32, o = (v%32)*4
        int i = v >> 5, o0 = (v & 31) * 4;
        f32x4 a = ((const f32x4*)wp)[v];
        Bs[(o0 + 0) * LDA + i] = f2bf(a.x);
        Bs[(o0 + 1) * LDA + i] = f2bf(a.y);
        Bs[(o0 + 2) * LDA + i] = f2bf(a.z);
        Bs[(o0 + 3) * LDA + i] = f2bf(a.w);
    }
    __syncthreads();

    const int wid = t >> 6, l = t & 63;
    const int wm = (wid >> 1) * 64, wn = (wid & 1) * 64;
    const int lr = l & 15, lk = (l >> 4) * 8;
    f32x4 acc[4][4] = {};
    #pragma unroll
    for (int ks = 0; ks < DIN; ks += 32) {
        s16x8 af[4], bf[4];
        #pragma unroll
        for (int i = 0; i < 4; ++i)
            af[i] = *(const s16x8*)(As + (wm + i * 16 + lr) * LDA + ks + lk);
        #pragma unroll
        for (int j = 0; j < 4; ++j)
            bf[j] = *(const s16x8*)(Bs + (wn + j * 16 + lr) * LDA + ks + lk);
        #pragma unroll
        for (int i = 0; i < 4; ++i)
            #pragma unroll
            for (int j = 0; j < 4; ++j)
                acc[i][j] = __builtin_amdgcn_mfma_f32_16x16x32_bf16(af[i], bf[j], acc[i][j], 0, 0, 0);
    }
    // Transposed store: lane's 4 acc regs are 4 consecutive n -> contiguous s16x4.
    unsigned short* sb = sT + (size_t)b * HO * NN;
    #pragma unroll
    for (int i = 0; i < 4; ++i)
        #pragma unroll
        for (int j = 0; j < 4; ++j) {
            int o = wn + j * 16 + lr;
            int n = nt * 128 + wm + i * 16 + (l >> 4) * 4;
            s16x4 st = { (short)f2bf(acc[i][j][0]), (short)f2bf(acc[i][j][1]),
                         (short)f2bf(acc[i][j][2]), (short)f2bf(acc[i][j][3]) };
            *(s16x4*)(sb + ((size_t)(h * DOUT + o)) * NN + n) = st;
        }
}

// ---------------------------------------------------------------------------
// K5: out[b][h][m][o] = tanh( sum_n adjn[b][m][n] * sT[b][h*128+o][n] + bias[h][o] )
// m97-structure GEMM-BT: 128x128 tile, BK=32, global_load_lds width 16,
// 4 waves x (4x4 16x16 frags), fused bias+tanh epilogue.
__global__ __launch_bounds__(256) void k_agg(
        const unsigned short* __restrict__ adjn, const unsigned short* __restrict__ sT,
        const float* __restrict__ bias, float* __restrict__ out) {
    __shared__ unsigned short As[128 * 32];
    __shared__ unsigned short Bs[128 * 32];
    const int mt = blockIdx.x, ct = blockIdx.y, b = blockIdx.z, t = threadIdx.x;

    const unsigned short* Ab = adjn + (size_t)b * NN * NN + (size_t)(mt * 128) * NN;
    const unsigned short* Bb = sT + (size_t)b * HO * NN + (size_t)(ct * 128) * NN;
    const int rr = t >> 2, cc = (t & 3) * 8;      // staging: row, col-within-BK
    const unsigned short* ga0 = Ab + (size_t)rr * NN + cc;
    const unsigned short* ga1 = Ab + (size_t)(rr + 64) * NN + cc;
    const unsigned short* gb0 = Bb + (size_t)rr * NN + cc;
    const unsigned short* gb1 = Bb + (size_t)(rr + 64) * NN + cc;
    unsigned short* la0 = As + t * 8;
    unsigned short* la1 = As + (t + 256) * 8;
    unsigned short* lb0 = Bs + t * 8;
    unsigned short* lb1 = Bs + (t + 256) * 8;

    const int wid = t >> 6, l = t & 63;
    const int wm = (wid >> 1) * 64, wn = (wid & 1) * 64;
    const int lr = l & 15, lk = (l >> 4) * 8;
    f32x4 acc[4][4] = {};

    for (int k0 = 0; k0 < NN; k0 += 32) {
        gload_lds16(ga0 + k0, la0);
        gload_lds16(ga1 + k0, la1);
        gload_lds16(gb0 + k0, lb0);
        gload_lds16(gb1 + k0, lb1);
        __syncthreads();
        s16x8 af[4], bf[4];
        #pragma unroll
        for (int i = 0; i < 4; ++i)
            af[i] = *(const s16x8*)(As + (wm + i * 16 + lr) * 32 + lk);
        #pragma unroll
        for (int j = 0; j < 4; ++j)
            bf[j] = *(const s16x8*)(Bs + (wn + j * 16 + lr) * 32 + lk);
        #pragma unroll
        for (int i = 0; i < 4; ++i)
            #pragma unroll
            for (int j = 0; j < 4; ++j)
                acc[i][j] = __builtin_amdgcn_mfma_f32_16x16x32_bf16(af[i], bf[j], acc[i][j], 0, 0, 0);
        __syncthreads();
    }

    #pragma unroll
    for (int j = 0; j < 4; ++j) {
        int c = ct * 128 + wn + j * 16 + lr;
        int h = c >> 7, o = c & (DOUT - 1);
        float bv = bias[h * DOUT + o];
        #pragma unroll
        for (int i = 0; i < 4; ++i) {
            int m = mt * 128 + wm + i * 16 + (l >> 4) * 4;
            float* op = out + (((size_t)b * H_ + h) * NN + m) * DOUT + o;
            #pragma unroll
            for (int r = 0; r < 4; ++r)
                op[(size_t)r * DOUT] = tanhf(acc[i][j][r] + bv);
        }
    }
}

// ---------------------------------------------------------------------------
extern "C" void kernel_launch(void* const* d_in, const int* in_sizes, int n_in,
                              void* d_out, int out_size, void* d_ws, size_t ws_size,
                              hipStream_t stream) {
    const float* x      = (const float*)d_in[0];   // [8,4,2048,128]
    const float* adj    = (const float*)d_in[1];   // [8,2048,2048]
    const float* pooled = (const float*)d_in[2];   // [8,128]
    const float* wts    = (const float*)d_in[3];   // [4,128,128]
    const float* bias   = (const float*)d_in[4];   // [4,128]

    float* out        = (float*)d_out;             // [8,4,2048,128]
    float* out_adj    = out + (size_t)B_ * H_ * NN * DOUT;            // +8388608
    float* out_pooled = out_adj + (size_t)B_ * NN * NN;               // +33554432

    char* ws = (char*)d_ws;
    unsigned short* sT   = (unsigned short*)ws;                        // 16 MiB
    unsigned short* adjn = (unsigned short*)(ws + 16777216);           // 64 MiB
    float* partial       = (float*)(ws + 16777216 + 67108864);         // 4 MiB
    float* dvec          = (float*)(ws + 16777216 + 67108864 + 4194304); // 64 KiB

    k_colsum_copy<<<dim3(64, B_), 256, 0, stream>>>(adj, out_adj, partial);
    k_finalize<<<64, 256, 0, stream>>>(partial, dvec, pooled, out_pooled);
    k_adjn<<<2048, 256, 0, stream>>>(adj, dvec, adjn);
    k_support<<<dim3(NN / 128, H_, B_), 256, 0, stream>>>(x, wts, sT);
    k_agg<<<dim3(NN / 128, HO / 128, B_), 256, 0, stream>>>(adjn, sT, bias, out);
}

// Round 3
// 388.185 us; speedup vs baseline: 1.0521x; 1.0521x over previous
//
#include <hip/hip_runtime.h>
#include <cstdint>
#include <cstddef>
#include <math.h>

#define B_ 8
#define H_ 4
#define NN 2048
#define DIN 128
#define DOUT 128
#define HO (H_ * DOUT)   // 512

typedef __attribute__((ext_vector_type(4))) float f32x4;
typedef __attribute__((ext_vector_type(8))) short s16x8;
typedef __attribute__((ext_vector_type(4))) short s16x4;

__device__ __forceinline__ unsigned short f2bf(float f) {
    union { float f; unsigned u; } v; v.f = f;
    unsigned r = v.u + 0x7fffu + ((v.u >> 16) & 1u);   // RNE
    return (unsigned short)(r >> 16);
}

__device__ __forceinline__ void gload_lds16(const void* g, void* l) {
    __builtin_amdgcn_global_load_lds(
        (const __attribute__((address_space(1))) unsigned int*)g,
        (__attribute__((address_space(3))) unsigned int*)l, 16, 0, 0);
}

__device__ __forceinline__ float fast_tanh(float x) {
    float xc = fminf(fmaxf(x, -15.f), 15.f);
    float e = __expf(2.f * xc);
    return (e - 1.f) / (e + 1.f);
}

// ---------------------------------------------------------------------------
// K1 (merged, 1024 blocks): bids 0..511   = colsum partials + adj copy
//                           bids 512..1023 = support GEMM  sT = bf16(x @ W)
__global__ void k_main1(
        const float* __restrict__ adj, float* __restrict__ out_adj,
        float* __restrict__ partial,
        const float* __restrict__ x, const float* __restrict__ w,
        unsigned short* __restrict__ sT) {
    const int bid = blockIdx.x, t = threadIdx.x;

    if (bid < 512) {
        // ---- colsum + copy (v1-verbatim) ----
        const int b = bid >> 6, chunk = bid & 63;
        const float* src = adj + (size_t)b * NN * NN;
        float* dst = out_adj + (size_t)b * NN * NN;
        f32x4 s0 = {0.f, 0.f, 0.f, 0.f}, s1 = {0.f, 0.f, 0.f, 0.f};
        const int r0 = chunk * 32;
        for (int r = r0; r < r0 + 32; ++r) {
            const f32x4* row = (const f32x4*)(src + (size_t)r * NN);
            f32x4* orow = (f32x4*)(dst + (size_t)r * NN);
            f32x4 a = row[t], c = row[t + 256];
            orow[t] = a; orow[t + 256] = c;
            s0 += a; s1 += c;
        }
        float* p = partial + ((size_t)chunk * B_ + b) * NN;
        *(f32x4*)(p + 4 * t) = s0;
        *(f32x4*)(p + 1024 + 4 * t) = s1;
        return;
    }

    // ---- support GEMM (v1-verbatim code, flat-bid decode) ----
    constexpr int LDA = DIN + 8;   // 136
    __shared__ unsigned short As[128 * LDA];
    __shared__ unsigned short Bs[DOUT * LDA];
    const int sid = bid - 512;
    const int nt = sid & 15, h = (sid >> 4) & 3, b = sid >> 6;

    const float* xp = x + (((size_t)b * H_ + h) * NN + (size_t)nt * 128) * DIN;
    #pragma unroll
    for (int it = 0; it < 16; ++it) {
        int v = t + it * 256;
        int row = v >> 5, c4 = (v & 31) * 4;
        f32x4 a = ((const f32x4*)xp)[v];
        s16x4 s = { (short)f2bf(a.x), (short)f2bf(a.y), (short)f2bf(a.z), (short)f2bf(a.w) };
        *(s16x4*)(As + row * LDA + c4) = s;
    }
    const float* wp = w + (size_t)h * DIN * DOUT;
    #pragma unroll
    for (int it = 0; it < 16; ++it) {
        int v = t + it * 256;
        int i = v >> 5, o0 = (v & 31) * 4;
        f32x4 a = ((const f32x4*)wp)[v];
        Bs[(o0 + 0) * LDA + i] = f2bf(a.x);
        Bs[(o0 + 1) * LDA + i] = f2bf(a.y);
        Bs[(o0 + 2) * LDA + i] = f2bf(a.z);
        Bs[(o0 + 3) * LDA + i] = f2bf(a.w);
    }
    __syncthreads();

    const int wid = t >> 6, l = t & 63;
    const int wm = (wid >> 1) * 64, wn = (wid & 1) * 64;
    const int lr = l & 15, lk = (l >> 4) * 8;
    f32x4 acc[4][4] = {};
    #pragma unroll
    for (int ks = 0; ks < DIN; ks += 32) {
        s16x8 af[4], bf[4];
        #pragma unroll
        for (int i = 0; i < 4; ++i)
            af[i] = *(const s16x8*)(As + (wm + i * 16 + lr) * LDA + ks + lk);
        #pragma unroll
        for (int j = 0; j < 4; ++j)
            bf[j] = *(const s16x8*)(Bs + (wn + j * 16 + lr) * LDA + ks + lk);
        #pragma unroll
        for (int i = 0; i < 4; ++i)
            #pragma unroll
            for (int j = 0; j < 4; ++j)
                acc[i][j] = __builtin_amdgcn_mfma_f32_16x16x32_bf16(af[i], bf[j], acc[i][j], 0, 0, 0);
    }
    unsigned short* sb = sT + (size_t)b * HO * NN;
    #pragma unroll
    for (int i = 0; i < 4; ++i)
        #pragma unroll
        for (int j = 0; j < 4; ++j) {
            int o = wn + j * 16 + lr;
            int n = nt * 128 + wm + i * 16 + (l >> 4) * 4;
            s16x4 st = { (short)f2bf(acc[i][j][0]), (short)f2bf(acc[i][j][1]),
                         (short)f2bf(acc[i][j][2]), (short)f2bf(acc[i][j][3]) };
            *(s16x4*)(sb + ((size_t)(h * DOUT + o)) * NN + n) = st;
        }
}

// ---------------------------------------------------------------------------
// K2: d = rsqrt(colsum); pooled copy. (v1-verbatim)
__global__ __launch_bounds__(256) void k_finalize(
        const float* __restrict__ partial, float* __restrict__ dvec,
        const float* __restrict__ pooled, float* __restrict__ out_pooled) {
    const int i = blockIdx.x * 256 + threadIdx.x;
    float s = 0.f;
    for (int c = 0; c < 64; ++c) s += partial[(size_t)c * (B_ * NN) + i];
    dvec[i] = 1.0f / sqrtf(s);
    if (i < B_ * DOUT) out_pooled[i] = pooled[i];
}

// ---------------------------------------------------------------------------
// K3: adjn = bf16(dm * adj * dn). (v1-verbatim)
__global__ __launch_bounds__(256) void k_adjn(
        const float* __restrict__ adj, const float* __restrict__ dvec,
        unsigned short* __restrict__ adjn) {
    const size_t total = (size_t)B_ * NN * NN / 4;
    const size_t stride = (size_t)gridDim.x * blockDim.x;
    for (size_t idx = (size_t)blockIdx.x * blockDim.x + threadIdx.x; idx < total; idx += stride) {
        size_t e = idx * 4;
        int b = (int)(e >> 22);
        int rem = (int)(e & ((1u << 22) - 1));
        int m = rem >> 11, n = rem & (NN - 1);
        f32x4 a = *(const f32x4*)(adj + e);
        float dm = dvec[b * NN + m];
        f32x4 dn = *(const f32x4*)(dvec + b * NN + n);
        f32x4 v = a * dm;
        v *= dn;
        s16x4 o = { (short)f2bf(v.x), (short)f2bf(v.y), (short)f2bf(v.z), (short)f2bf(v.w) };
        *(s16x4*)(adjn + e) = o;
    }
}

// ---------------------------------------------------------------------------
// K4: agg GEMM (m97 structure) + bias + tanh.
// Batch-per-XCD swizzle: XCD x (= bid&7) owns batch x; the 4 ct-tiles sharing
// an A-panel are consecutive within the XCD -> L2-resident reuse.
__global__ __launch_bounds__(256) void k_agg(
        const unsigned short* __restrict__ adjn, const unsigned short* __restrict__ sT,
        const float* __restrict__ bias, float* __restrict__ out) {
    __shared__ unsigned short As[128 * 32];
    __shared__ unsigned short Bs[128 * 32];
    const int bid = blockIdx.x, t = threadIdx.x;
    const int b = bid & 7, mt = (bid >> 5) & 15, ct = (bid >> 3) & 3;

    const unsigned short* Ab = adjn + (size_t)b * NN * NN + (size_t)(mt * 128) * NN;
    const unsigned short* Bb = sT + (size_t)b * HO * NN + (size_t)(ct * 128) * NN;
    const int rr = t >> 2, cc = (t & 3) * 8;
    const unsigned short* ga0 = Ab + (size_t)rr * NN + cc;
    const unsigned short* ga1 = Ab + (size_t)(rr + 64) * NN + cc;
    const unsigned short* gb0 = Bb + (size_t)rr * NN + cc;
    const unsigned short* gb1 = Bb + (size_t)(rr + 64) * NN + cc;
    unsigned short* la0 = As + t * 8;
    unsigned short* la1 = As + (t + 256) * 8;
    unsigned short* lb0 = Bs + t * 8;
    unsigned short* lb1 = Bs + (t + 256) * 8;

    const int wid = t >> 6, l = t & 63;
    const int wm = (wid >> 1) * 64, wn = (wid & 1) * 64;
    const int lr = l & 15, lk = (l >> 4) * 8;
    f32x4 acc[4][4] = {};

    for (int k0 = 0; k0 < NN; k0 += 32) {
        gload_lds16(ga0 + k0, la0);
        gload_lds16(ga1 + k0, la1);
        gload_lds16(gb0 + k0, lb0);
        gload_lds16(gb1 + k0, lb1);
        __syncthreads();
        s16x8 af[4], bf[4];
        #pragma unroll
        for (int i = 0; i < 4; ++i)
            af[i] = *(const s16x8*)(As + (wm + i * 16 + lr) * 32 + lk);
        #pragma unroll
        for (int j = 0; j < 4; ++j)
            bf[j] = *(const s16x8*)(Bs + (wn + j * 16 + lr) * 32 + lk);
        #pragma unroll
        for (int i = 0; i < 4; ++i)
            #pragma unroll
            for (int j = 0; j < 4; ++j)
                acc[i][j] = __builtin_amdgcn_mfma_f32_16x16x32_bf16(af[i], bf[j], acc[i][j], 0, 0, 0);
        __syncthreads();
    }

    #pragma unroll
    for (int j = 0; j < 4; ++j) {
        int c = ct * 128 + wn + j * 16 + lr;
        int h = c >> 7, o = c & (DOUT - 1);
        float bv = bias[h * DOUT + o];
        #pragma unroll
        for (int i = 0; i < 4; ++i) {
            int m = mt * 128 + wm + i * 16 + (l >> 4) * 4;
            float* op = out + (((size_t)b * H_ + h) * NN + m) * DOUT + o;
            #pragma unroll
            for (int r = 0; r < 4; ++r)
                op[(size_t)r * DOUT] = fast_tanh(acc[i][j][r] + bv);
        }
    }
}

// ---------------------------------------------------------------------------
extern "C" void kernel_launch(void* const* d_in, const int* in_sizes, int n_in,
                              void* d_out, int out_size, void* d_ws, size_t ws_size,
                              hipStream_t stream) {
    (void)in_sizes; (void)n_in; (void)out_size; (void)ws_size;
    const float* x      = (const float*)d_in[0];   // [8,4,2048,128]
    const float* adj    = (const float*)d_in[1];   // [8,2048,2048]
    const float* pooled = (const float*)d_in[2];   // [8,128]
    const float* wts    = (const float*)d_in[3];   // [4,128,128]
    const float* bias   = (const float*)d_in[4];   // [4,128]

    float* out        = (float*)d_out;                                  // [8,4,2048,128]
    float* out_adj    = out + (size_t)B_ * H_ * NN * DOUT;              // [8,2048,2048]
    float* out_pooled = out_adj + (size_t)B_ * NN * NN;                 // [8,128]

    char* ws = (char*)d_ws;
    unsigned short* sT   = (unsigned short*)ws;                          // 16 MiB
    unsigned short* adjn = (unsigned short*)(ws + 16777216);             // 64 MiB
    float* partial       = (float*)(ws + 16777216 + 67108864);           // 4 MiB
    float* dvec          = (float*)(ws + 16777216 + 67108864 + 4194304); // 64 KiB

    k_main1<<<1024, 256, 0, stream>>>(adj, out_adj, partial, x, wts, sT);
    k_finalize<<<64, 256, 0, stream>>>(partial, dvec, pooled, out_pooled);
    k_adjn<<<2048, 256, 0, stream>>>(adj, dvec, adjn);
    k_agg<<<512, 256, 0, stream>>>(adjn, sT, bias, out);
}